// Round 13
// baseline (109.716 us; speedup 1.0000x reference)
//
#include <hip/hip_runtime.h>
#include <hip/hip_bf16.h>

#define B_DIM 512
#define D_DIM 256
#define C_DIM 100000
#define LAMB 1000.0f
#define NPANEL 391            // ceil(C/256)

using bf16x8 = __attribute__((ext_vector_type(8))) short;
using f32x4  = __attribute__((ext_vector_type(4))) float;

__device__ __forceinline__ short f2bf(float f) {
  unsigned u = __builtin_bit_cast(unsigned, f);
  u += 0x7FFFu + ((u >> 16) & 1u);      // round-to-nearest-even
  return (short)(u >> 16);
}

// async global->LDS, 16B per lane; LDS dest = wave-uniform base + lane*16
__device__ __forceinline__ void gload_lds16(const void* g, void* l) {
  __builtin_amdgcn_global_load_lds(
      (__attribute__((address_space(1))) void*)g,
      (__attribute__((address_space(3))) void*)l, 16, 0, 0);
}

// Kernel 1: xlen per row + bf16 x, pre-swizzled (byte ^= (row&7)<<4) so the
// GEMM's linear LDS staging + swizzled ds_read_b128 is bank-conflict-minimal.
__global__ __launch_bounds__(256) void prep_x(const float* __restrict__ x,
                                              unsigned short* __restrict__ x_swz,
                                              float* __restrict__ xlen) {
  int wv = threadIdx.x >> 6, lane = threadIdx.x & 63;
  int row = blockIdx.x * 4 + wv;
  float4 v = *(const float4*)(x + row * D_DIM + lane * 4);
  float ss = v.x * v.x + v.y * v.y + v.z * v.z + v.w * v.w;
#pragma unroll
  for (int m = 1; m < 64; m <<= 1) ss += __shfl_xor(ss, m);
  if (lane == 0) xlen[row] = sqrtf(ss);
  ushort4 u;
  u.x = (unsigned short)f2bf(v.x);
  u.y = (unsigned short)f2bf(v.y);
  u.z = (unsigned short)f2bf(v.z);
  u.w = (unsigned short)f2bf(v.w);
  int byteoff = row * 512 + ((lane * 8) ^ ((row & 7) << 4));
  *(ushort4*)((char*)x_swz + byteoff) = u;
}

// Kernel 2: GEMM — write-locality restructure. 8-wave (512-thread) blocks,
// 256 cols x 256 rows each (391 panels x 2 halves = 782 blocks).
// Every r1-r11 variant (sync/balance/occupancy all varied, all ~88us) shared
// two locality sins this fixes:
//  (1) 512B-per-row write granules (4 waves x 128B) -> now 8 waves x 128B =
//      1KB contiguous per row per chunk, waves kept in phase by the chunk
//      barrier -> L2 evicts full adjacent-line runs.
//  (2) all blocks staging the SAME 16KB x-chunk each phase (lockstep sweep)
//      -> per-block chunk rotation (chunk+bid)&7 spreads reads over 16
//      distinct chunks and widens the write band.
// Wave-level code (fw frags, swizzled ds_read, MFMA, float4 stores) is
// identical to r4. VGPR ~112 -> 2 blocks/CU = 16 waves/CU (= r4).
// R12 BUG (fixed): prologue LDS dest had "i*8192+wv*1024" added twice ->
// chunk rot(0) staged to wrong addresses -> absmax = max(xlen).
__global__ __launch_bounds__(512) void gemm_bf16(
    const float* __restrict__ W, const unsigned short* __restrict__ xb,
    const float* __restrict__ xlen, float* __restrict__ out) {
  __shared__ unsigned short xs[2][32 * 256];   // 2 x 16 KB (swizzled rows)
  __shared__ float xlen_s[256];

  const int tid = threadIdx.x;
  const int lane = tid & 63, wv = tid >> 6;
  const int l15 = lane & 15, g = lane >> 4;

  const int bid = blockIdx.x;
  const int panel = bid >> 1, half = bid & 1;
  const int bn0 = panel * 256 + wv * 32;       // this wave's 32 cols
  const int row0 = half * 256;                 // this block's 256 rows

  if (tid < 256) xlen_s[tid] = xlen[row0 + tid];

  // chunk rotation: block processes physical chunks rot(0..7)
#define ROT(c) (((c) + bid) & 7)

  // prologue: stage chunk rot(0) (512 threads x 16B x 2 = 16 KB)
#pragma unroll
  for (int i = 0; i < 2; ++i)
    gload_lds16((const char*)xb + (row0 + ROT(0) * 32) * 512 + i * 8192 + tid * 16,
                (char*)xs[0] + i * 8192 + wv * 1024);

  // ---- Phase 1: W cols -> A-frags (bf16) + inv_wlen (fp32), r4-proven ----
  // A-frag: lane holds A[row][k], row = lane&15 -> W-col, k = kg*32+g*8+j.
  bf16x8 fw[2][8];
  float invw4[2][4];   // inv_wlen for W-col = bn0 + it*16 + g*4 + r
#pragma unroll
  for (int it = 0; it < 2; ++it) {
    int col = bn0 + it * 16 + l15;
    if (col >= C_DIM) col = C_DIM - 1;        // clamp; stores are guarded
    const float* wr = W + (size_t)col * D_DIM + g * 8;
    float ss = 0.f;
#pragma unroll
    for (int kg = 0; kg < 8; ++kg) {
      float4 a = *(const float4*)(wr + kg * 32);
      float4 b = *(const float4*)(wr + kg * 32 + 4);
      ss += a.x * a.x + a.y * a.y + a.z * a.z + a.w * a.w
          + b.x * b.x + b.y * b.y + b.z * b.z + b.w * b.w;
      bf16x8 f;
      f[0] = f2bf(a.x); f[1] = f2bf(a.y); f[2] = f2bf(a.z); f[3] = f2bf(a.w);
      f[4] = f2bf(b.x); f[5] = f2bf(b.y); f[6] = f2bf(b.z); f[7] = f2bf(b.w);
      fw[it][kg] = f;
    }
    ss += __shfl_xor(ss, 16);                 // reduce across the 4 g-groups
    ss += __shfl_xor(ss, 32);
    float iw = 1.0f / sqrtf(ss);              // lane l15 holds col bn0+it*16+l15
#pragma unroll
    for (int r = 0; r < 4; ++r) invw4[it][r] = __shfl(iw, g * 4 + r);
  }

  __syncthreads();                            // chunk rot(0) staged

  // ---- Main loop: 8 chunks of 32 rows, 2-phase double buffer ----
  int buf = 0;
  for (int c = 0; c < 8; ++c) {
    if (c < 7) {                              // stage next chunk first
#pragma unroll
      for (int i = 0; i < 2; ++i)
        gload_lds16((const char*)xb + (row0 + ROT(c + 1) * 32) * 512 + i * 8192 + tid * 16,
                    (char*)xs[buf ^ 1] + i * 8192 + wv * 1024);
    }

#pragma unroll
    for (int jtl = 0; jtl < 2; ++jtl) {
      const int lr = jtl * 16 + l15;          // row within chunk
      const int row = row0 + ROT(c) * 32 + lr;
      const float xl = xlen_s[row - row0];
      const char* xp = (const char*)xs[buf] + lr * 512;
      const int swz = (l15 & 7) << 4;
      bf16x8 fx[8];
#pragma unroll
      for (int kg = 0; kg < 8; ++kg)
        fx[kg] = *(const bf16x8*)(xp + ((kg * 64 + g * 16) ^ swz));

      f32x4 acc0 = {}, acc1 = {};
#pragma unroll
      for (int kg = 0; kg < 8; ++kg) {
        acc0 = __builtin_amdgcn_mfma_f32_16x16x32_bf16(fw[0][kg], fx[kg], acc0, 0, 0, 0);
        acc1 = __builtin_amdgcn_mfma_f32_16x16x32_bf16(fw[1][kg], fx[kg], acc1, 0, 0, 0);
      }

      // epilogue: feat = clamp(dot * inv_wlen, -xlen, xlen); float4 stores
      const size_t orow = (size_t)row * C_DIM;
#pragma unroll
      for (int it = 0; it < 2; ++it) {
        const f32x4& a = it ? acc1 : acc0;
        int wc = bn0 + it * 16 + g * 4;       // D row = g*4 + r -> W-col
        if (wc < C_DIM) {                     // C%4==0 -> float4 all-or-nothing
          float4 v;
          v.x = fminf(fmaxf(a[0] * invw4[it][0], -xl), xl);
          v.y = fminf(fmaxf(a[1] * invw4[it][1], -xl), xl);
          v.z = fminf(fmaxf(a[2] * invw4[it][2], -xl), xl);
          v.w = fminf(fmaxf(a[3] * invw4[it][3], -xl), xl);
          *(float4*)(out + orow + wc) = v;
        }
      }
    }

    __syncthreads();                          // next buffer staged; buf free
    buf ^= 1;
  }
#undef ROT
}

// Kernel 3: exact fp32 recompute of the 512 label positions (margin math).
__global__ __launch_bounds__(256) void fix_labels(const float* __restrict__ x,
                                                  const float* __restrict__ W,
                                                  const int* __restrict__ y,
                                                  float* __restrict__ out) {
  int wv = threadIdx.x >> 6, lane = threadIdx.x & 63;
  int b = blockIdx.x * 4 + wv;
  int c = y[b];
  float4 wvv = *(const float4*)(W + (size_t)c * D_DIM + lane * 4);
  float4 xv  = *(const float4*)(x + b * D_DIM + lane * 4);
  float dt = wvv.x * xv.x + wvv.y * xv.y + wvv.z * xv.z + wvv.w * xv.w;
  float sw = wvv.x * wvv.x + wvv.y * wvv.y + wvv.z * wvv.z + wvv.w * wvv.w;
  float sx = xv.x * xv.x + xv.y * xv.y + xv.z * xv.z + xv.w * xv.w;
#pragma unroll
  for (int m = 1; m < 64; m <<= 1) {
    dt += __shfl_xor(dt, m);
    sw += __shfl_xor(sw, m);
    sx += __shfl_xor(sx, m);
  }
  if (lane == 0) {
    float xl = sqrtf(sx), wl = sqrtf(sw);
    float cth = dt / (xl * wl);
    cth = fminf(fmaxf(cth, -1.f), 1.f);
    float c2 = cth * cth;
    float cm = 8.f * c2 * c2 - 8.f * c2 + 1.f;          // cos(4t) Chebyshev
    float k = floorf(4.0f * acosf(cth) / 3.14159265358979323846f);
    float sgn = (((int)k) & 1) ? -1.f : 1.f;
    float phi = sgn * cm - 2.f * k;
    float feat = cth * xl;
    out[(size_t)b * C_DIM + c] = feat + (phi * xl - feat) / (1.f + LAMB);
  }
}

extern "C" void kernel_launch(void* const* d_in, const int* in_sizes, int n_in,
                              void* d_out, int out_size, void* d_ws, size_t ws_size,
                              hipStream_t stream) {
  const float* x = (const float*)d_in[0];
  const float* W = (const float*)d_in[1];
  const int*   y = (const int*)d_in[2];
  float* out = (float*)d_out;

  unsigned short* xb = (unsigned short*)d_ws;                    // 256 KB (swizzled bf16 x)
  float* xlen = (float*)((char*)d_ws + B_DIM * D_DIM * 2);       // 2 KB

  prep_x<<<B_DIM / 4, 256, 0, stream>>>(x, xb, xlen);
  gemm_bf16<<<NPANEL * 2, 512, 0, stream>>>(W, xb, xlen, out);   // 782 blocks
  fix_labels<<<B_DIM / 4, 256, 0, stream>>>(x, W, y, out);
}

// Round 14
// 102.458 us; speedup vs baseline: 1.0708x; 1.0708x over previous
//
#include <hip/hip_runtime.h>
#include <hip/hip_bf16.h>

#define B_DIM 512
#define D_DIM 256
#define C_DIM 100000
#define LAMB 1000.0f

using bf16x8 = __attribute__((ext_vector_type(8))) short;
using f32x4  = __attribute__((ext_vector_type(4))) float;

__device__ __forceinline__ short f2bf(float f) {
  unsigned u = __builtin_bit_cast(unsigned, f);
  u += 0x7FFFu + ((u >> 16) & 1u);      // round-to-nearest-even
  return (short)(u >> 16);
}

// async global->LDS, 16B per lane; LDS dest = wave-uniform base + lane*16
__device__ __forceinline__ void gload_lds16(const void* g, void* l) {
  __builtin_amdgcn_global_load_lds(
      (__attribute__((address_space(1))) void*)g,
      (__attribute__((address_space(3))) void*)l, 16, 0, 0);
}

// Kernel 1: xlen per row + bf16 x, pre-swizzled (byte ^= (row&7)<<4).
__global__ __launch_bounds__(256) void prep_x(const float* __restrict__ x,
                                              unsigned short* __restrict__ x_swz,
                                              float* __restrict__ xlen) {
  int wv = threadIdx.x >> 6, lane = threadIdx.x & 63;
  int row = blockIdx.x * 4 + wv;
  float4 v = *(const float4*)(x + row * D_DIM + lane * 4);
  float ss = v.x * v.x + v.y * v.y + v.z * v.z + v.w * v.w;
#pragma unroll
  for (int m = 1; m < 64; m <<= 1) ss += __shfl_xor(ss, m);
  if (lane == 0) xlen[row] = sqrtf(ss);
  ushort4 u;
  u.x = (unsigned short)f2bf(v.x);
  u.y = (unsigned short)f2bf(v.y);
  u.z = (unsigned short)f2bf(v.z);
  u.w = (unsigned short)f2bf(v.w);
  int byteoff = row * 512 + ((lane * 8) ^ ((row & 7) << 4));
  *(ushort4*)((char*)x_swz + byteoff) = u;
}

// Kernel 1b: pure-stream W pre-normalize. One wave per W row (col of the
// cos matrix): read 1KB fp32, sumsq-reduce, write 512B normalized bf16.
// Moves 102MB of read + all normalize math OUT of the GEMM, which becomes
// a nearly-pure write stream (r4's phase-1 serialized ~20us of reads ahead
// of the writes; that serialization is the target).
__global__ __launch_bounds__(256) void prep_w(const float* __restrict__ W,
                                              unsigned short* __restrict__ wb) {
  int wv = threadIdx.x >> 6, lane = threadIdx.x & 63;
  int col = blockIdx.x * 4 + wv;              // 25000 blocks x 4 cols
  const float4 v = *(const float4*)(W + (size_t)col * D_DIM + lane * 4);
  float ss = v.x * v.x + v.y * v.y + v.z * v.z + v.w * v.w;
#pragma unroll
  for (int m = 1; m < 64; m <<= 1) ss += __shfl_xor(ss, m);
  const float iw = 1.0f / sqrtf(ss);
  ushort4 u;
  u.x = (unsigned short)f2bf(v.x * iw);
  u.y = (unsigned short)f2bf(v.y * iw);
  u.z = (unsigned short)f2bf(v.z * iw);
  u.w = (unsigned short)f2bf(v.w * iw);
  *(ushort4*)(wb + (size_t)col * D_DIM + lane * 4) = u;
}

// Kernel 2a (big-ws path): r4 main loop verbatim, but fw frags load directly
// from pre-normalized bf16 wb (16 x 16B loads, ~0.5us/block) — no sumsq, no
// shuffles, no invw4. Epilogue = clamp(acc, +-xlen).
__global__ __launch_bounds__(256) void gemm_lite(
    const unsigned short* __restrict__ wb, const unsigned short* __restrict__ xb,
    const float* __restrict__ xlen, float* __restrict__ out) {
  __shared__ unsigned short xs[2][32 * 256];   // 2 x 16 KB (swizzled rows)
  __shared__ float xlen_s[B_DIM];

  const int tid = threadIdx.x;
  const int lane = tid & 63, wv = tid >> 6;
  const int l15 = lane & 15, g = lane >> 4;
  const int bn0 = blockIdx.x * 128 + wv * 32;

  for (int i = tid; i < B_DIM; i += 256) xlen_s[i] = xlen[i];

  // prologue: stage chunk 0
#pragma unroll
  for (int i = 0; i < 4; ++i)
    gload_lds16((const char*)xb + i * 4096 + tid * 16,
                (char*)xs[0] + i * 4096 + wv * 1024);

  // W A-frags: lane holds A[row][k], row=lane&15 -> W-col, k=kg*32+g*8+j.
  bf16x8 fw[2][8];
#pragma unroll
  for (int it = 0; it < 2; ++it) {
    int col = bn0 + it * 16 + l15;
    if (col >= C_DIM) col = C_DIM - 1;        // clamp; stores are guarded
    const unsigned short* wr = wb + (size_t)col * D_DIM + g * 8;
#pragma unroll
    for (int kg = 0; kg < 8; ++kg)
      fw[it][kg] = *(const bf16x8*)(wr + kg * 32);
  }

  __syncthreads();                            // chunk 0 staged

  // ---- Main loop: 16 chunks of 32 rows, 2-phase double buffer (r4) ----
  int buf = 0;
  for (int chunk = 0; chunk < 16; ++chunk) {
    if (chunk < 15) {
#pragma unroll
      for (int i = 0; i < 4; ++i)
        gload_lds16((const char*)xb + (chunk + 1) * 16384 + i * 4096 + tid * 16,
                    (char*)xs[buf ^ 1] + i * 4096 + wv * 1024);
    }

#pragma unroll
    for (int jtl = 0; jtl < 2; ++jtl) {
      const int xrow = chunk * 32 + jtl * 16 + l15;
      const float xl = xlen_s[xrow];
      const char* xp = (const char*)xs[buf] + (jtl * 16 + l15) * 512;
      const int swz = (l15 & 7) << 4;
      bf16x8 fx[8];
#pragma unroll
      for (int kg = 0; kg < 8; ++kg)
        fx[kg] = *(const bf16x8*)(xp + ((kg * 64 + g * 16) ^ swz));

      f32x4 acc0 = {}, acc1 = {};
#pragma unroll
      for (int kg = 0; kg < 8; ++kg) {
        acc0 = __builtin_amdgcn_mfma_f32_16x16x32_bf16(fw[0][kg], fx[kg], acc0, 0, 0, 0);
        acc1 = __builtin_amdgcn_mfma_f32_16x16x32_bf16(fw[1][kg], fx[kg], acc1, 0, 0, 0);
      }

      const size_t orow = (size_t)xrow * C_DIM;
#pragma unroll
      for (int it = 0; it < 2; ++it) {
        const f32x4& a = it ? acc1 : acc0;
        int wc = bn0 + it * 16 + g * 4;
        if (wc < C_DIM) {
          float4 v;
          v.x = fminf(fmaxf(a[0], -xl), xl);
          v.y = fminf(fmaxf(a[1], -xl), xl);
          v.z = fminf(fmaxf(a[2], -xl), xl);
          v.w = fminf(fmaxf(a[3], -xl), xl);
          *(float4*)(out + orow + wc) = v;
        }
      }
    }

    __syncthreads();
    buf ^= 1;
  }
}

// Kernel 2b (fallback, small ws): r4 gemm verbatim (phase-1 in-kernel).
__global__ __launch_bounds__(256) void gemm_full(
    const float* __restrict__ W, const unsigned short* __restrict__ xb,
    const float* __restrict__ xlen, float* __restrict__ out) {
  __shared__ unsigned short xs[2][32 * 256];
  __shared__ float xlen_s[B_DIM];

  const int tid = threadIdx.x;
  const int lane = tid & 63, wv = tid >> 6;
  const int l15 = lane & 15, g = lane >> 4;
  const int bn0 = blockIdx.x * 128 + wv * 32;

  for (int i = tid; i < B_DIM; i += 256) xlen_s[i] = xlen[i];

#pragma unroll
  for (int i = 0; i < 4; ++i)
    gload_lds16((const char*)xb + i * 4096 + tid * 16,
                (char*)xs[0] + i * 4096 + wv * 1024);

  bf16x8 fw[2][8];
  float invw4[2][4];
#pragma unroll
  for (int it = 0; it < 2; ++it) {
    int col = bn0 + it * 16 + l15;
    if (col >= C_DIM) col = C_DIM - 1;
    const float* wr = W + (size_t)col * D_DIM + g * 8;
    float ss = 0.f;
#pragma unroll
    for (int kg = 0; kg < 8; ++kg) {
      float4 a = *(const float4*)(wr + kg * 32);
      float4 b = *(const float4*)(wr + kg * 32 + 4);
      ss += a.x * a.x + a.y * a.y + a.z * a.z + a.w * a.w
          + b.x * b.x + b.y * b.y + b.z * b.z + b.w * b.w;
      bf16x8 f;
      f[0] = f2bf(a.x); f[1] = f2bf(a.y); f[2] = f2bf(a.z); f[3] = f2bf(a.w);
      f[4] = f2bf(b.x); f[5] = f2bf(b.y); f[6] = f2bf(b.z); f[7] = f2bf(b.w);
      fw[it][kg] = f;
    }
    ss += __shfl_xor(ss, 16);
    ss += __shfl_xor(ss, 32);
    float iw = 1.0f / sqrtf(ss);
#pragma unroll
    for (int r = 0; r < 4; ++r) invw4[it][r] = __shfl(iw, g * 4 + r);
  }

  __syncthreads();

  int buf = 0;
  for (int chunk = 0; chunk < 16; ++chunk) {
    if (chunk < 15) {
#pragma unroll
      for (int i = 0; i < 4; ++i)
        gload_lds16((const char*)xb + (chunk + 1) * 16384 + i * 4096 + tid * 16,
                    (char*)xs[buf ^ 1] + i * 4096 + wv * 1024);
    }

#pragma unroll
    for (int jtl = 0; jtl < 2; ++jtl) {
      const int xrow = chunk * 32 + jtl * 16 + l15;
      const float xl = xlen_s[xrow];
      const char* xp = (const char*)xs[buf] + (jtl * 16 + l15) * 512;
      const int swz = (l15 & 7) << 4;
      bf16x8 fx[8];
#pragma unroll
      for (int kg = 0; kg < 8; ++kg)
        fx[kg] = *(const bf16x8*)(xp + ((kg * 64 + g * 16) ^ swz));

      f32x4 acc0 = {}, acc1 = {};
#pragma unroll
      for (int kg = 0; kg < 8; ++kg) {
        acc0 = __builtin_amdgcn_mfma_f32_16x16x32_bf16(fw[0][kg], fx[kg], acc0, 0, 0, 0);
        acc1 = __builtin_amdgcn_mfma_f32_16x16x32_bf16(fw[1][kg], fx[kg], acc1, 0, 0, 0);
      }

      const size_t orow = (size_t)xrow * C_DIM;
#pragma unroll
      for (int it = 0; it < 2; ++it) {
        const f32x4& a = it ? acc1 : acc0;
        int wc = bn0 + it * 16 + g * 4;
        if (wc < C_DIM) {
          float4 v;
          v.x = fminf(fmaxf(a[0] * invw4[it][0], -xl), xl);
          v.y = fminf(fmaxf(a[1] * invw4[it][1], -xl), xl);
          v.z = fminf(fmaxf(a[2] * invw4[it][2], -xl), xl);
          v.w = fminf(fmaxf(a[3] * invw4[it][3], -xl), xl);
          *(float4*)(out + orow + wc) = v;
        }
      }
    }

    __syncthreads();
    buf ^= 1;
  }
}

// Kernel 3: exact fp32 recompute of the 512 label positions (margin math).
__global__ __launch_bounds__(256) void fix_labels(const float* __restrict__ x,
                                                  const float* __restrict__ W,
                                                  const int* __restrict__ y,
                                                  float* __restrict__ out) {
  int wv = threadIdx.x >> 6, lane = threadIdx.x & 63;
  int b = blockIdx.x * 4 + wv;
  int c = y[b];
  float4 wvv = *(const float4*)(W + (size_t)c * D_DIM + lane * 4);
  float4 xv  = *(const float4*)(x + b * D_DIM + lane * 4);
  float dt = wvv.x * xv.x + wvv.y * xv.y + wvv.z * xv.z + wvv.w * xv.w;
  float sw = wvv.x * wvv.x + wvv.y * wvv.y + wvv.z * wvv.z + wvv.w * wvv.w;
  float sx = xv.x * xv.x + xv.y * xv.y + xv.z * xv.z + xv.w * xv.w;
#pragma unroll
  for (int m = 1; m < 64; m <<= 1) {
    dt += __shfl_xor(dt, m);
    sw += __shfl_xor(sw, m);
    sx += __shfl_xor(sx, m);
  }
  if (lane == 0) {
    float xl = sqrtf(sx), wl = sqrtf(sw);
    float cth = dt / (xl * wl);
    cth = fminf(fmaxf(cth, -1.f), 1.f);
    float c2 = cth * cth;
    float cm = 8.f * c2 * c2 - 8.f * c2 + 1.f;          // cos(4t) Chebyshev
    float k = floorf(4.0f * acosf(cth) / 3.14159265358979323846f);
    float sgn = (((int)k) & 1) ? -1.f : 1.f;
    float phi = sgn * cm - 2.f * k;
    float feat = cth * xl;
    out[(size_t)b * C_DIM + c] = feat + (phi * xl - feat) / (1.f + LAMB);
  }
}

extern "C" void kernel_launch(void* const* d_in, const int* in_sizes, int n_in,
                              void* d_out, int out_size, void* d_ws, size_t ws_size,
                              hipStream_t stream) {
  const float* x = (const float*)d_in[0];
  const float* W = (const float*)d_in[1];
  const int*   y = (const int*)d_in[2];
  float* out = (float*)d_out;

  unsigned short* xb = (unsigned short*)d_ws;                    // 256 KB (swizzled bf16 x)
  float* xlen = (float*)((char*)d_ws + 262144);                  // 2 KB
  const size_t WB_OFF = 264192;
  const size_t WB_BYTES = (size_t)C_DIM * D_DIM * 2;             // 51.2 MB

  prep_x<<<B_DIM / 4, 256, 0, stream>>>(x, xb, xlen);
  if (ws_size >= WB_OFF + WB_BYTES) {
    unsigned short* wwb = (unsigned short*)((char*)d_ws + WB_OFF);
    prep_w<<<C_DIM / 4, 256, 0, stream>>>(W, wwb);
    gemm_lite<<<(C_DIM + 127) / 128, 256, 0, stream>>>(wwb, xb, xlen, out);
  } else {
    gemm_full<<<(C_DIM + 127) / 128, 256, 0, stream>>>(W, xb, xlen, out);
  }
  fix_labels<<<B_DIM / 4, 256, 0, stream>>>(x, W, y, out);
}

// Round 15
// 89.923 us; speedup vs baseline: 1.2201x; 1.1394x over previous
//
#include <hip/hip_runtime.h>
#include <hip/hip_bf16.h>

#define B_DIM 512
#define D_DIM 256
#define C_DIM 100000
#define LAMB 1000.0f

using bf16x8 = __attribute__((ext_vector_type(8))) short;
using f32x4  = __attribute__((ext_vector_type(4))) float;

__device__ __forceinline__ short f2bf(float f) {
  unsigned u = __builtin_bit_cast(unsigned, f);
  u += 0x7FFFu + ((u >> 16) & 1u);      // round-to-nearest-even
  return (short)(u >> 16);
}

// async global->LDS, 16B per lane; LDS dest = wave-uniform base + lane*16
__device__ __forceinline__ void gload_lds16(const void* g, void* l) {
  __builtin_amdgcn_global_load_lds(
      (__attribute__((address_space(1))) void*)g,
      (__attribute__((address_space(3))) void*)l, 16, 0, 0);
}

// Kernel 1: xlen per row + bf16 x, pre-swizzled (byte ^= (row&7)<<4).
__global__ __launch_bounds__(256) void prep_x(const float* __restrict__ x,
                                              unsigned short* __restrict__ x_swz,
                                              float* __restrict__ xlen) {
  int wv = threadIdx.x >> 6, lane = threadIdx.x & 63;
  int row = blockIdx.x * 4 + wv;
  float4 v = *(const float4*)(x + row * D_DIM + lane * 4);
  float ss = v.x * v.x + v.y * v.y + v.z * v.z + v.w * v.w;
#pragma unroll
  for (int m = 1; m < 64; m <<= 1) ss += __shfl_xor(ss, m);
  if (lane == 0) xlen[row] = sqrtf(ss);
  ushort4 u;
  u.x = (unsigned short)f2bf(v.x);
  u.y = (unsigned short)f2bf(v.y);
  u.z = (unsigned short)f2bf(v.z);
  u.w = (unsigned short)f2bf(v.w);
  int byteoff = row * 512 + ((lane * 8) ^ ((row & 7) << 4));
  *(ushort4*)((char*)x_swz + byteoff) = u;
}

// Kernel 2: GEMM = r4 skeleton + TRANSPOSE EPILOGUE through LDS.
// Every r1-r14 variant ran at ~3.5 TB/s effective while the float4 copy
// µbench (same read/write mix, sequential) hits 6.3 TB/s. The shared
// difference: our stores scatter 64 lanes over 16 output rows (400 KB
// stride) = 16x64B transactions per instruction. Here each chunk's 32x128
// f32 result goes acc -> tb[32][132] (padded: 2-way write banks, free) ->
// read back row-contiguous -> each store instr covers 2 contiguous 512B
// runs (8x fewer, 8x wider transactions).
// Barrier A is lgkm-only (raw s_barrier): the next-chunk gload_lds prefetch
// stays in flight across it (no vmcnt drain added vs r4).
__global__ __launch_bounds__(256) void gemm_bf16(
    const float* __restrict__ W, const unsigned short* __restrict__ xb,
    const float* __restrict__ xlen, float* __restrict__ out) {
  __shared__ unsigned short xs[2][32 * 256];   // 32 KB (swizzled x rows)
  __shared__ float tb[32 * 132];               // 16.5 KB transpose buffer
  __shared__ float xlen_s[B_DIM];              // 2 KB

  const int tid = threadIdx.x;
  const int lane = tid & 63, wv = tid >> 6;
  const int l15 = lane & 15, g = lane >> 4;
  const int bcol0 = blockIdx.x * 128;
  const int bn0 = bcol0 + wv * 32;

  for (int i = tid; i < B_DIM; i += 256) xlen_s[i] = xlen[i];

  // prologue: stage chunk 0
#pragma unroll
  for (int i = 0; i < 4; ++i)
    gload_lds16((const char*)xb + i * 4096 + tid * 16,
                (char*)xs[0] + i * 4096 + wv * 1024);

  // ---- Phase 1: W cols -> A-frags (bf16) + inv_wlen (fp32), r4-proven ----
  // A-frag: lane holds A[row][k], row = lane&15 -> W-col, k = kg*32+g*8+j.
  bf16x8 fw[2][8];
  float invw4[2][4];   // inv_wlen for W-col = bn0 + it*16 + g*4 + r
#pragma unroll
  for (int it = 0; it < 2; ++it) {
    int col = bn0 + it * 16 + l15;
    if (col >= C_DIM) col = C_DIM - 1;        // clamp; stores are guarded
    const float* wr = W + (size_t)col * D_DIM + g * 8;
    float ss = 0.f;
#pragma unroll
    for (int kg = 0; kg < 8; ++kg) {
      float4 a = *(const float4*)(wr + kg * 32);
      float4 b = *(const float4*)(wr + kg * 32 + 4);
      ss += a.x * a.x + a.y * a.y + a.z * a.z + a.w * a.w
          + b.x * b.x + b.y * b.y + b.z * b.z + b.w * b.w;
      bf16x8 f;
      f[0] = f2bf(a.x); f[1] = f2bf(a.y); f[2] = f2bf(a.z); f[3] = f2bf(a.w);
      f[4] = f2bf(b.x); f[5] = f2bf(b.y); f[6] = f2bf(b.z); f[7] = f2bf(b.w);
      fw[it][kg] = f;
    }
    ss += __shfl_xor(ss, 16);                 // reduce across the 4 g-groups
    ss += __shfl_xor(ss, 32);
    float iw = 1.0f / sqrtf(ss);              // lane l15 holds col bn0+it*16+l15
#pragma unroll
    for (int r = 0; r < 4; ++r) invw4[it][r] = __shfl(iw, g * 4 + r);
  }

  __syncthreads();                            // chunk 0 staged

  // ---- Main loop: 16 chunks of 32 rows ----
  int buf = 0;
  for (int chunk = 0; chunk < 16; ++chunk) {
    if (chunk < 15) {                         // prefetch next chunk
#pragma unroll
      for (int i = 0; i < 4; ++i)
        gload_lds16((const char*)xb + (chunk + 1) * 16384 + i * 4096 + tid * 16,
                    (char*)xs[buf ^ 1] + i * 4096 + wv * 1024);
    }

    // compute the whole 32-row chunk (acc: 16 regs, static-indexed)
    f32x4 acc[2][2] = {};                     // [jtl][it]
#pragma unroll
    for (int jtl = 0; jtl < 2; ++jtl) {
      const char* xp = (const char*)xs[buf] + (jtl * 16 + l15) * 512;
      const int swz = (l15 & 7) << 4;
      bf16x8 fx[8];
#pragma unroll
      for (int kg = 0; kg < 8; ++kg)
        fx[kg] = *(const bf16x8*)(xp + ((kg * 64 + g * 16) ^ swz));
#pragma unroll
      for (int kg = 0; kg < 8; ++kg) {
        acc[jtl][0] = __builtin_amdgcn_mfma_f32_16x16x32_bf16(fw[0][kg], fx[kg], acc[jtl][0], 0, 0, 0);
        acc[jtl][1] = __builtin_amdgcn_mfma_f32_16x16x32_bf16(fw[1][kg], fx[kg], acc[jtl][1], 0, 0, 0);
      }
    }

    // epilogue math + transpose write: tb[lrow][wcol_local] (row pad +4)
#pragma unroll
    for (int jtl = 0; jtl < 2; ++jtl) {
      const int lrow = jtl * 16 + l15;
      const float xl = xlen_s[chunk * 32 + lrow];
#pragma unroll
      for (int it = 0; it < 2; ++it) {
        float4 v;
        v.x = fminf(fmaxf(acc[jtl][it][0] * invw4[it][0], -xl), xl);
        v.y = fminf(fmaxf(acc[jtl][it][1] * invw4[it][1], -xl), xl);
        v.z = fminf(fmaxf(acc[jtl][it][2] * invw4[it][2], -xl), xl);
        v.w = fminf(fmaxf(acc[jtl][it][3] * invw4[it][3], -xl), xl);
        *(float4*)&tb[lrow * 132 + wv * 32 + it * 16 + g * 4] = v;
      }
    }

    // barrier A: LDS-only — prefetch gloads stay in flight (no vmcnt drain)
    asm volatile("s_waitcnt lgkmcnt(0)" ::: "memory");
    __builtin_amdgcn_s_barrier();

    // read back row-contiguous, store 512B runs (2 per instruction)
    {
      const int c16 = tid & 31;               // 16B col unit within 512B row
      const int rbase = tid >> 5;             // 0..7
      const int gcol = bcol0 + c16 * 4;
      const bool ok = gcol < C_DIM;           // C%4==0 -> float4 all-or-nothing
#pragma unroll
      for (int p = 0; p < 4; ++p) {
        const int lrow = p * 8 + rbase;
        float4 v = *(const float4*)&tb[lrow * 132 + c16 * 4];
        if (ok)
          *(float4*)(out + (size_t)(chunk * 32 + lrow) * C_DIM + gcol) = v;
      }
    }

    __syncthreads();                          // gloads drained; tb reusable
    buf ^= 1;
  }
}

// Kernel 3: exact fp32 recompute of the 512 label positions (margin math).
__global__ __launch_bounds__(256) void fix_labels(const float* __restrict__ x,
                                                  const float* __restrict__ W,
                                                  const int* __restrict__ y,
                                                  float* __restrict__ out) {
  int wv = threadIdx.x >> 6, lane = threadIdx.x & 63;
  int b = blockIdx.x * 4 + wv;
  int c = y[b];
  float4 wvv = *(const float4*)(W + (size_t)c * D_DIM + lane * 4);
  float4 xv  = *(const float4*)(x + b * D_DIM + lane * 4);
  float dt = wvv.x * xv.x + wvv.y * xv.y + wvv.z * xv.z + wvv.w * xv.w;
  float sw = wvv.x * wvv.x + wvv.y * wvv.y + wvv.z * wvv.z + wvv.w * wvv.w;
  float sx = xv.x * xv.x + xv.y * xv.y + xv.z * xv.z + xv.w * xv.w;
#pragma unroll
  for (int m = 1; m < 64; m <<= 1) {
    dt += __shfl_xor(dt, m);
    sw += __shfl_xor(sw, m);
    sx += __shfl_xor(sx, m);
  }
  if (lane == 0) {
    float xl = sqrtf(sx), wl = sqrtf(sw);
    float cth = dt / (xl * wl);
    cth = fminf(fmaxf(cth, -1.f), 1.f);
    float c2 = cth * cth;
    float cm = 8.f * c2 * c2 - 8.f * c2 + 1.f;          // cos(4t) Chebyshev
    float k = floorf(4.0f * acosf(cth) / 3.14159265358979323846f);
    float sgn = (((int)k) & 1) ? -1.f : 1.f;
    float phi = sgn * cm - 2.f * k;
    float feat = cth * xl;
    out[(size_t)b * C_DIM + c] = feat + (phi * xl - feat) / (1.f + LAMB);
  }
}

extern "C" void kernel_launch(void* const* d_in, const int* in_sizes, int n_in,
                              void* d_out, int out_size, void* d_ws, size_t ws_size,
                              hipStream_t stream) {
  const float* x = (const float*)d_in[0];
  const float* W = (const float*)d_in[1];
  const int*   y = (const int*)d_in[2];
  float* out = (float*)d_out;

  unsigned short* xb = (unsigned short*)d_ws;                    // 256 KB (swizzled bf16 x)
  float* xlen = (float*)((char*)d_ws + B_DIM * D_DIM * 2);       // 2 KB

  prep_x<<<B_DIM / 4, 256, 0, stream>>>(x, xb, xlen);
  gemm_bf16<<<(C_DIM + 127) / 128, 256, 0, stream>>>(W, xb, xlen, out);
  fix_labels<<<B_DIM / 4, 256, 0, stream>>>(x, W, y, out);
}

// Round 17
// 78.318 us; speedup vs baseline: 1.4009x; 1.1482x over previous
//
#include <hip/hip_runtime.h>
#include <hip/hip_bf16.h>

#define B_DIM 512
#define D_DIM 256
#define C_DIM 100000
#define LAMB 1000.0f

using bf16x8 = __attribute__((ext_vector_type(8))) short;
using f32x4  = __attribute__((ext_vector_type(4))) float;

__device__ __forceinline__ short f2bf(float f) {
  unsigned u = __builtin_bit_cast(unsigned, f);
  u += 0x7FFFu + ((u >> 16) & 1u);      // round-to-nearest-even
  return (short)(u >> 16);
}

// async global->LDS, 16B per lane; LDS dest = wave-uniform base + lane*16
__device__ __forceinline__ void gload_lds16(const void* g, void* l) {
  __builtin_amdgcn_global_load_lds(
      (__attribute__((address_space(1))) void*)g,
      (__attribute__((address_space(3))) void*)l, 16, 0, 0);
}

// Kernel 1: xlen per row + bf16 x, pre-swizzled (byte ^= (row&7)<<4).
__global__ __launch_bounds__(256) void prep_x(const float* __restrict__ x,
                                              unsigned short* __restrict__ x_swz,
                                              float* __restrict__ xlen) {
  int wv = threadIdx.x >> 6, lane = threadIdx.x & 63;
  int row = blockIdx.x * 4 + wv;
  float4 v = *(const float4*)(x + row * D_DIM + lane * 4);
  float ss = v.x * v.x + v.y * v.y + v.z * v.z + v.w * v.w;
#pragma unroll
  for (int m = 1; m < 64; m <<= 1) ss += __shfl_xor(ss, m);
  if (lane == 0) xlen[row] = sqrtf(ss);
  ushort4 u;
  u.x = (unsigned short)f2bf(v.x);
  u.y = (unsigned short)f2bf(v.y);
  u.z = (unsigned short)f2bf(v.z);
  u.w = (unsigned short)f2bf(v.w);
  int byteoff = row * 512 + ((lane * 8) ^ ((row & 7) << 4));
  *(ushort4*)((char*)x_swz + byteoff) = u;
}

// Kernel 2: r15 (transpose epilogue, 512B runs) + NON-TEMPORAL output stores.
// r15 proved store granularity moves the needle (88->82us gemm). The
// residual vs the 6.9 TB/s fill: writes pass through L2 as ~800 blocks'
// interleaved dirty lines — the EVICTION engine, not issue order, sequences
// DRAM traffic, re-scattering the 512B runs. nt stores stream past L2 so
// DRAM sees issue order (= contiguous-run order). Output has zero cache
// reuse, so nothing is lost. Single-variable A/B vs r15.
// R16 fix: __builtin_nontemporal_store needs a true vector type (f32x4),
// not HIP's float4 struct.
__global__ __launch_bounds__(256) void gemm_bf16(
    const float* __restrict__ W, const unsigned short* __restrict__ xb,
    const float* __restrict__ xlen, float* __restrict__ out) {
  __shared__ unsigned short xs[2][32 * 256];   // 32 KB (swizzled x rows)
  __shared__ float tb[32 * 132];               // 16.5 KB transpose buffer
  __shared__ float xlen_s[B_DIM];              // 2 KB

  const int tid = threadIdx.x;
  const int lane = tid & 63, wv = tid >> 6;
  const int l15 = lane & 15, g = lane >> 4;
  const int bcol0 = blockIdx.x * 128;
  const int bn0 = bcol0 + wv * 32;

  for (int i = tid; i < B_DIM; i += 256) xlen_s[i] = xlen[i];

  // prologue: stage chunk 0
#pragma unroll
  for (int i = 0; i < 4; ++i)
    gload_lds16((const char*)xb + i * 4096 + tid * 16,
                (char*)xs[0] + i * 4096 + wv * 1024);

  // ---- Phase 1: W cols -> A-frags (bf16) + inv_wlen (fp32), r4-proven ----
  // A-frag: lane holds A[row][k], row = lane&15 -> W-col, k = kg*32+g*8+j.
  bf16x8 fw[2][8];
  float invw4[2][4];   // inv_wlen for W-col = bn0 + it*16 + g*4 + r
#pragma unroll
  for (int it = 0; it < 2; ++it) {
    int col = bn0 + it * 16 + l15;
    if (col >= C_DIM) col = C_DIM - 1;        // clamp; stores are guarded
    const float* wr = W + (size_t)col * D_DIM + g * 8;
    float ss = 0.f;
#pragma unroll
    for (int kg = 0; kg < 8; ++kg) {
      float4 a = *(const float4*)(wr + kg * 32);
      float4 b = *(const float4*)(wr + kg * 32 + 4);
      ss += a.x * a.x + a.y * a.y + a.z * a.z + a.w * a.w
          + b.x * b.x + b.y * b.y + b.z * b.z + b.w * b.w;
      bf16x8 f;
      f[0] = f2bf(a.x); f[1] = f2bf(a.y); f[2] = f2bf(a.z); f[3] = f2bf(a.w);
      f[4] = f2bf(b.x); f[5] = f2bf(b.y); f[6] = f2bf(b.z); f[7] = f2bf(b.w);
      fw[it][kg] = f;
    }
    ss += __shfl_xor(ss, 16);                 // reduce across the 4 g-groups
    ss += __shfl_xor(ss, 32);
    float iw = 1.0f / sqrtf(ss);              // lane l15 holds col bn0+it*16+l15
#pragma unroll
    for (int r = 0; r < 4; ++r) invw4[it][r] = __shfl(iw, g * 4 + r);
  }

  __syncthreads();                            // chunk 0 staged

  // ---- Main loop: 16 chunks of 32 rows ----
  int buf = 0;
  for (int chunk = 0; chunk < 16; ++chunk) {
    if (chunk < 15) {                         // prefetch next chunk
#pragma unroll
      for (int i = 0; i < 4; ++i)
        gload_lds16((const char*)xb + (chunk + 1) * 16384 + i * 4096 + tid * 16,
                    (char*)xs[buf ^ 1] + i * 4096 + wv * 1024);
    }

    // compute the whole 32-row chunk (acc: 16 regs, static-indexed)
    f32x4 acc[2][2] = {};                     // [jtl][it]
#pragma unroll
    for (int jtl = 0; jtl < 2; ++jtl) {
      const char* xp = (const char*)xs[buf] + (jtl * 16 + l15) * 512;
      const int swz = (l15 & 7) << 4;
      bf16x8 fx[8];
#pragma unroll
      for (int kg = 0; kg < 8; ++kg)
        fx[kg] = *(const bf16x8*)(xp + ((kg * 64 + g * 16) ^ swz));
#pragma unroll
      for (int kg = 0; kg < 8; ++kg) {
        acc[jtl][0] = __builtin_amdgcn_mfma_f32_16x16x32_bf16(fw[0][kg], fx[kg], acc[jtl][0], 0, 0, 0);
        acc[jtl][1] = __builtin_amdgcn_mfma_f32_16x16x32_bf16(fw[1][kg], fx[kg], acc[jtl][1], 0, 0, 0);
      }
    }

    // epilogue math + transpose write: tb[lrow][wcol_local] (row pad +4)
#pragma unroll
    for (int jtl = 0; jtl < 2; ++jtl) {
      const int lrow = jtl * 16 + l15;
      const float xl = xlen_s[chunk * 32 + lrow];
#pragma unroll
      for (int it = 0; it < 2; ++it) {
        float4 v;
        v.x = fminf(fmaxf(acc[jtl][it][0] * invw4[it][0], -xl), xl);
        v.y = fminf(fmaxf(acc[jtl][it][1] * invw4[it][1], -xl), xl);
        v.z = fminf(fmaxf(acc[jtl][it][2] * invw4[it][2], -xl), xl);
        v.w = fminf(fmaxf(acc[jtl][it][3] * invw4[it][3], -xl), xl);
        *(float4*)&tb[lrow * 132 + wv * 32 + it * 16 + g * 4] = v;
      }
    }

    // barrier A: LDS-only — prefetch gloads stay in flight (no vmcnt drain)
    asm volatile("s_waitcnt lgkmcnt(0)" ::: "memory");
    __builtin_amdgcn_s_barrier();

    // read back row-contiguous, store 512B runs NON-TEMPORAL (bypass L2)
    {
      const int c16 = tid & 31;               // 16B col unit within 512B row
      const int rbase = tid >> 5;             // 0..7
      const int gcol = bcol0 + c16 * 4;
      const bool ok = gcol < C_DIM;           // C%4==0 -> float4 all-or-nothing
#pragma unroll
      for (int p = 0; p < 4; ++p) {
        const int lrow = p * 8 + rbase;
        f32x4 v = *(const f32x4*)&tb[lrow * 132 + c16 * 4];
        if (ok)
          __builtin_nontemporal_store(
              v, (f32x4*)(out + (size_t)(chunk * 32 + lrow) * C_DIM + gcol));
      }
    }

    __syncthreads();                          // gloads drained; tb reusable
    buf ^= 1;
  }
}

// Kernel 3: exact fp32 recompute of the 512 label positions (margin math).
__global__ __launch_bounds__(256) void fix_labels(const float* __restrict__ x,
                                                  const float* __restrict__ W,
                                                  const int* __restrict__ y,
                                                  float* __restrict__ out) {
  int wv = threadIdx.x >> 6, lane = threadIdx.x & 63;
  int b = blockIdx.x * 4 + wv;
  int c = y[b];
  float4 wvv = *(const float4*)(W + (size_t)c * D_DIM + lane * 4);
  float4 xv  = *(const float4*)(x + b * D_DIM + lane * 4);
  float dt = wvv.x * xv.x + wvv.y * xv.y + wvv.z * xv.z + wvv.w * xv.w;
  float sw = wvv.x * wvv.x + wvv.y * wvv.y + wvv.z * wvv.z + wvv.w * wvv.w;
  float sx = xv.x * xv.x + xv.y * xv.y + xv.z * xv.z + xv.w * xv.w;
#pragma unroll
  for (int m = 1; m < 64; m <<= 1) {
    dt += __shfl_xor(dt, m);
    sw += __shfl_xor(sw, m);
    sx += __shfl_xor(sx, m);
  }
  if (lane == 0) {
    float xl = sqrtf(sx), wl = sqrtf(sw);
    float cth = dt / (xl * wl);
    cth = fminf(fmaxf(cth, -1.f), 1.f);
    float c2 = cth * cth;
    float cm = 8.f * c2 * c2 - 8.f * c2 + 1.f;          // cos(4t) Chebyshev
    float k = floorf(4.0f * acosf(cth) / 3.14159265358979323846f);
    float sgn = (((int)k) & 1) ? -1.f : 1.f;
    float phi = sgn * cm - 2.f * k;
    float feat = cth * xl;
    out[(size_t)b * C_DIM + c] = feat + (phi * xl - feat) / (1.f + LAMB);
  }
}

extern "C" void kernel_launch(void* const* d_in, const int* in_sizes, int n_in,
                              void* d_out, int out_size, void* d_ws, size_t ws_size,
                              hipStream_t stream) {
  const float* x = (const float*)d_in[0];
  const float* W = (const float*)d_in[1];
  const int*   y = (const int*)d_in[2];
  float* out = (float*)d_out;

  unsigned short* xb = (unsigned short*)d_ws;                    // 256 KB (swizzled bf16 x)
  float* xlen = (float*)((char*)d_ws + B_DIM * D_DIM * 2);       // 2 KB

  prep_x<<<B_DIM / 4, 256, 0, stream>>>(x, xb, xlen);
  gemm_bf16<<<(C_DIM + 127) / 128, 256, 0, stream>>>(W, xb, xlen, out);
  fix_labels<<<B_DIM / 4, 256, 0, stream>>>(x, W, y, out);
}

// Round 18
// 78.028 us; speedup vs baseline: 1.4061x; 1.0037x over previous
//
#include <hip/hip_runtime.h>
#include <hip/hip_bf16.h>

#define B_DIM 512
#define D_DIM 256
#define C_DIM 100000
#define LAMB 1000.0f

using bf16x8 = __attribute__((ext_vector_type(8))) short;
using f32x4  = __attribute__((ext_vector_type(4))) float;

__device__ __forceinline__ short f2bf(float f) {
  unsigned u = __builtin_bit_cast(unsigned, f);
  u += 0x7FFFu + ((u >> 16) & 1u);      // round-to-nearest-even
  return (short)(u >> 16);
}

// async global->LDS, 16B per lane; LDS dest = wave-uniform base + lane*16
__device__ __forceinline__ void gload_lds16(const void* g, void* l) {
  __builtin_amdgcn_global_load_lds(
      (__attribute__((address_space(1))) void*)g,
      (__attribute__((address_space(3))) void*)l, 16, 0, 0);
}

// Kernel 1: xlen per row + bf16 x, pre-swizzled (byte ^= (row&7)<<4).
__global__ __launch_bounds__(256) void prep_x(const float* __restrict__ x,
                                              unsigned short* __restrict__ x_swz,
                                              float* __restrict__ xlen) {
  int wv = threadIdx.x >> 6, lane = threadIdx.x & 63;
  int row = blockIdx.x * 4 + wv;
  float4 v = *(const float4*)(x + row * D_DIM + lane * 4);
  float ss = v.x * v.x + v.y * v.y + v.z * v.z + v.w * v.w;
#pragma unroll
  for (int m = 1; m < 64; m <<= 1) ss += __shfl_xor(ss, m);
  if (lane == 0) xlen[row] = sqrtf(ss);
  ushort4 u;
  u.x = (unsigned short)f2bf(v.x);
  u.y = (unsigned short)f2bf(v.y);
  u.z = (unsigned short)f2bf(v.z);
  u.w = (unsigned short)f2bf(v.w);
  int byteoff = row * 512 + ((lane * 8) ^ ((row & 7) << 4));
  *(ushort4*)((char*)x_swz + byteoff) = u;
}

// Kernel 2: r17 (transpose epilogue + nt stores) + COUNTED end-of-chunk
// barrier. r17's __syncthreads drained vmcnt(0) each chunk — including the
// 4 nt stores, whose acks now come from the MEMORY CONTROLLER (~600-900cy)
// instead of L2 (~200cy). That drain is 16x/block on the critical path.
// Per-chunk VMEM issue order = [4 prefetch gloads]...[4 nt stores]; in-order
// retirement means s_waitcnt vmcnt(4) retires through the gloads (and last
// chunk's stores, which had a full chunk of slack) and leaves this chunk's
// nt stores in flight across the raw s_barrier. Last chunk: no barrier
// (kernel end drains). (r5's counted-vmcnt null was pre-nt — acks were
// cheap then; doesn't transfer.)
__global__ __launch_bounds__(256) void gemm_bf16(
    const float* __restrict__ W, const unsigned short* __restrict__ xb,
    const float* __restrict__ xlen, float* __restrict__ out) {
  __shared__ unsigned short xs[2][32 * 256];   // 32 KB (swizzled x rows)
  __shared__ float tb[32 * 132];               // 16.5 KB transpose buffer
  __shared__ float xlen_s[B_DIM];              // 2 KB

  const int tid = threadIdx.x;
  const int lane = tid & 63, wv = tid >> 6;
  const int l15 = lane & 15, g = lane >> 4;
  const int bcol0 = blockIdx.x * 128;
  const int bn0 = bcol0 + wv * 32;

  for (int i = tid; i < B_DIM; i += 256) xlen_s[i] = xlen[i];

  // prologue: stage chunk 0
#pragma unroll
  for (int i = 0; i < 4; ++i)
    gload_lds16((const char*)xb + i * 4096 + tid * 16,
                (char*)xs[0] + i * 4096 + wv * 1024);

  // ---- Phase 1: W cols -> A-frags (bf16) + inv_wlen (fp32), r4-proven ----
  // A-frag: lane holds A[row][k], row = lane&15 -> W-col, k = kg*32+g*8+j.
  bf16x8 fw[2][8];
  float invw4[2][4];   // inv_wlen for W-col = bn0 + it*16 + g*4 + r
#pragma unroll
  for (int it = 0; it < 2; ++it) {
    int col = bn0 + it * 16 + l15;
    if (col >= C_DIM) col = C_DIM - 1;        // clamp; stores are guarded
    const float* wr = W + (size_t)col * D_DIM + g * 8;
    float ss = 0.f;
#pragma unroll
    for (int kg = 0; kg < 8; ++kg) {
      float4 a = *(const float4*)(wr + kg * 32);
      float4 b = *(const float4*)(wr + kg * 32 + 4);
      ss += a.x * a.x + a.y * a.y + a.z * a.z + a.w * a.w
          + b.x * b.x + b.y * b.y + b.z * b.z + b.w * b.w;
      bf16x8 f;
      f[0] = f2bf(a.x); f[1] = f2bf(a.y); f[2] = f2bf(a.z); f[3] = f2bf(a.w);
      f[4] = f2bf(b.x); f[5] = f2bf(b.y); f[6] = f2bf(b.z); f[7] = f2bf(b.w);
      fw[it][kg] = f;
    }
    ss += __shfl_xor(ss, 16);                 // reduce across the 4 g-groups
    ss += __shfl_xor(ss, 32);
    float iw = 1.0f / sqrtf(ss);              // lane l15 holds col bn0+it*16+l15
#pragma unroll
    for (int r = 0; r < 4; ++r) invw4[it][r] = __shfl(iw, g * 4 + r);
  }

  __syncthreads();                            // chunk 0 staged (once; full drain ok)

  // ---- Main loop: 16 chunks of 32 rows ----
  int buf = 0;
  for (int chunk = 0; chunk < 16; ++chunk) {
    if (chunk < 15) {                         // prefetch next chunk
#pragma unroll
      for (int i = 0; i < 4; ++i)
        gload_lds16((const char*)xb + (chunk + 1) * 16384 + i * 4096 + tid * 16,
                    (char*)xs[buf ^ 1] + i * 4096 + wv * 1024);
    }
    __builtin_amdgcn_sched_barrier(0);        // gloads stay above

    // compute the whole 32-row chunk (acc: 16 regs, static-indexed)
    f32x4 acc[2][2] = {};                     // [jtl][it]
#pragma unroll
    for (int jtl = 0; jtl < 2; ++jtl) {
      const char* xp = (const char*)xs[buf] + (jtl * 16 + l15) * 512;
      const int swz = (l15 & 7) << 4;
      bf16x8 fx[8];
#pragma unroll
      for (int kg = 0; kg < 8; ++kg)
        fx[kg] = *(const bf16x8*)(xp + ((kg * 64 + g * 16) ^ swz));
#pragma unroll
      for (int kg = 0; kg < 8; ++kg) {
        acc[jtl][0] = __builtin_amdgcn_mfma_f32_16x16x32_bf16(fw[0][kg], fx[kg], acc[jtl][0], 0, 0, 0);
        acc[jtl][1] = __builtin_amdgcn_mfma_f32_16x16x32_bf16(fw[1][kg], fx[kg], acc[jtl][1], 0, 0, 0);
      }
    }

    // epilogue math + transpose write: tb[lrow][wcol_local] (row pad +4)
#pragma unroll
    for (int jtl = 0; jtl < 2; ++jtl) {
      const int lrow = jtl * 16 + l15;
      const float xl = xlen_s[chunk * 32 + lrow];
#pragma unroll
      for (int it = 0; it < 2; ++it) {
        float4 v;
        v.x = fminf(fmaxf(acc[jtl][it][0] * invw4[it][0], -xl), xl);
        v.y = fminf(fmaxf(acc[jtl][it][1] * invw4[it][1], -xl), xl);
        v.z = fminf(fmaxf(acc[jtl][it][2] * invw4[it][2], -xl), xl);
        v.w = fminf(fmaxf(acc[jtl][it][3] * invw4[it][3], -xl), xl);
        *(float4*)&tb[lrow * 132 + wv * 32 + it * 16 + g * 4] = v;
      }
    }

    // barrier A: LDS-only — prefetch gloads stay in flight (no vmcnt drain)
    asm volatile("s_waitcnt lgkmcnt(0)" ::: "memory");
    __builtin_amdgcn_s_barrier();

    // read back row-contiguous, store 512B runs NON-TEMPORAL (bypass L2)
    {
      const int c16 = tid & 31;               // 16B col unit within 512B row
      const int rbase = tid >> 5;             // 0..7
      const int gcol = bcol0 + c16 * 4;
      const bool ok = gcol < C_DIM;           // C%4==0 -> float4 all-or-nothing
#pragma unroll
      for (int p = 0; p < 4; ++p) {
        const int lrow = p * 8 + rbase;
        f32x4 v = *(const f32x4*)&tb[lrow * 132 + c16 * 4];
        if (ok)
          __builtin_nontemporal_store(
              v, (f32x4*)(out + (size_t)(chunk * 32 + lrow) * C_DIM + gcol));
      }
    }

    // end-of-chunk: counted wait — retire prefetch gloads (oldest), leave
    // this chunk's 4 nt stores in flight. No barrier after the last chunk.
    if (chunk < 15) {
      __builtin_amdgcn_sched_barrier(0);      // stores stay above
      asm volatile("s_waitcnt vmcnt(4)" ::: "memory");
      __builtin_amdgcn_s_barrier();
      __builtin_amdgcn_sched_barrier(0);
    }
    buf ^= 1;
  }
}

// Kernel 3: exact fp32 recompute of the 512 label positions (margin math).
__global__ __launch_bounds__(256) void fix_labels(const float* __restrict__ x,
                                                  const float* __restrict__ W,
                                                  const int* __restrict__ y,
                                                  float* __restrict__ out) {
  int wv = threadIdx.x >> 6, lane = threadIdx.x & 63;
  int b = blockIdx.x * 4 + wv;
  int c = y[b];
  float4 wvv = *(const float4*)(W + (size_t)c * D_DIM + lane * 4);
  float4 xv  = *(const float4*)(x + b * D_DIM + lane * 4);
  float dt = wvv.x * xv.x + wvv.y * xv.y + wvv.z * xv.z + wvv.w * xv.w;
  float sw = wvv.x * wvv.x + wvv.y * wvv.y + wvv.z * wvv.z + wvv.w * wvv.w;
  float sx = xv.x * xv.x + xv.y * xv.y + xv.z * xv.z + xv.w * xv.w;
#pragma unroll
  for (int m = 1; m < 64; m <<= 1) {
    dt += __shfl_xor(dt, m);
    sw += __shfl_xor(sw, m);
    sx += __shfl_xor(sx, m);
  }
  if (lane == 0) {
    float xl = sqrtf(sx), wl = sqrtf(sw);
    float cth = dt / (xl * wl);
    cth = fminf(fmaxf(cth, -1.f), 1.f);
    float c2 = cth * cth;
    float cm = 8.f * c2 * c2 - 8.f * c2 + 1.f;          // cos(4t) Chebyshev
    float k = floorf(4.0f * acosf(cth) / 3.14159265358979323846f);
    float sgn = (((int)k) & 1) ? -1.f : 1.f;
    float phi = sgn * cm - 2.f * k;
    float feat = cth * xl;
    out[(size_t)b * C_DIM + c] = feat + (phi * xl - feat) / (1.f + LAMB);
  }
}

extern "C" void kernel_launch(void* const* d_in, const int* in_sizes, int n_in,
                              void* d_out, int out_size, void* d_ws, size_t ws_size,
                              hipStream_t stream) {
  const float* x = (const float*)d_in[0];
  const float* W = (const float*)d_in[1];
  const int*   y = (const int*)d_in[2];
  float* out = (float*)d_out;

  unsigned short* xb = (unsigned short*)d_ws;                    // 256 KB (swizzled bf16 x)
  float* xlen = (float*)((char*)d_ws + B_DIM * D_DIM * 2);       // 2 KB

  prep_x<<<B_DIM / 4, 256, 0, stream>>>(x, xb, xlen);
  gemm_bf16<<<(C_DIM + 127) / 128, 256, 0, stream>>>(W, xb, xlen, out);
  fix_labels<<<B_DIM / 4, 256, 0, stream>>>(x, W, y, out);
}